// Round 1
// baseline (68.321 us; speedup 1.0000x reference)
//
#include <hip/hip_runtime.h>

typedef float v4f __attribute__((ext_vector_type(4)));
typedef float v2f __attribute__((ext_vector_type(2)));

#define LOG2E  1.4426950408889634f
#define NLOG2E (-1.4426950408889634f)
#define C2L2E  2.8853900817779268f   // 2*log2(e)
#define LN2    0.6931471805599453f

__device__ __forceinline__ float fexp2(float x){ return __builtin_amdgcn_exp2f(x); }
__device__ __forceinline__ float flog2(float x){ return __builtin_amdgcn_logf(x); }
__device__ __forceinline__ float frcp (float x){ return __builtin_amdgcn_rcpf(x); }
__device__ __forceinline__ float hsum(v4f v){ return (v.x+v.y)+(v.z+v.w); }

// ---------------------------------------------------------------------------
// prep: bid 0..127  : A/B = (x @ W1half (+b1)) * 2log2e   (X[2048x128] @ W[128x256])
//       bid 128..191: xpT = (x @ Wp)^T                    (X[2048x128] @ Wp[128x128])
//       bid 192..199: sq[row] = ||x_row||^2
// ---------------------------------------------------------------------------
__global__ __launch_bounds__(256) void prep_kernel(
    const float* __restrict__ x, const float* __restrict__ W1,
    const float* __restrict__ b1, const float* __restrict__ Wp,
    float* __restrict__ sq, float* __restrict__ Abuf,
    float* __restrict__ Bbuf, float* __restrict__ xpT)
{
  const int bid = blockIdx.x, t = threadIdx.x;
  if (bid >= 192) {                       // ---- sq ----
    int row = (bid - 192) * 256 + t;      // 0..2047
    const v4f* xv = (const v4f*)(x + row * 128);
    float s = 0.f;
#pragma unroll
    for (int q = 0; q < 32; q++) { v4f v = xv[q]; s += hsum(v * v); }
    sq[row] = s;
    return;
  }
  __shared__ v4f Xs[64 * 9];              // 64 rows x 8 f4, pad 9, slot-swizzled
  __shared__ v4f Ws[32 * 16];             // 32 dd  x 16 f4 (64 cols)
  const bool isAB = bid < 128;
  int it, ct;
  if (isAB) { it = bid >> 2; ct = bid & 3; }
  else      { int q = bid - 128; it = q >> 1; ct = q & 1; }
  const int row0 = it * 64;
  const int tx = t & 15, ty = t >> 4;
  const int r0 = ty * 4, c0 = tx * 4;
  v4f acc[4] = {};                        // acc[i] over 4 cols

  for (int dd0 = 0; dd0 < 128; dd0 += 32) {
    __syncthreads();
#pragma unroll
    for (int s2 = 0; s2 < 2; s2++) {      // stage X (coalesced), swizzled slot
      int idx = t + s2 * 256;
      int row = idx >> 3, k4 = idx & 7;
      v4f v = *(const v4f*)(x + (row0 + row) * 128 + dd0 + k4 * 4);
      Xs[row * 9 + ((k4 + (row >> 2)) & 7)] = v;
    }
#pragma unroll
    for (int s2 = 0; s2 < 2; s2++) {      // stage W (f4 along cols)
      int idx = t + s2 * 256;
      int dd = idx >> 4, cf4 = idx & 15;
      v4f v;
      if (isAB) {
        int cl = cf4 * 4; int half = cl >> 5; int k = cl & 31;
        v = *(const v4f*)(W1 + (ct * 256 + half * 128 + dd0 + dd) * 32 + k);
      } else {
        v = *(const v4f*)(Wp + (dd0 + dd) * 128 + ct * 64 + cf4 * 4);
      }
      Ws[dd * 16 + cf4] = v;
    }
    __syncthreads();
#pragma unroll
    for (int dd4 = 0; dd4 < 8; dd4++) {
      int sa = (dd4 + ty) & 7;
      v4f a0 = Xs[(r0 + 0) * 9 + sa], a1 = Xs[(r0 + 1) * 9 + sa];
      v4f a2 = Xs[(r0 + 2) * 9 + sa], a3 = Xs[(r0 + 3) * 9 + sa];
#pragma unroll
      for (int u = 0; u < 4; u++) {
        v4f bv = Ws[(dd4 * 4 + u) * 16 + tx];
        acc[0] += a0[u] * bv; acc[1] += a1[u] * bv;
        acc[2] += a2[u] * bv; acc[3] += a3[u] * bv;
      }
    }
  }

  if (isAB) {
    const int h = ct; const int half = c0 >> 5; const int k = c0 & 31;
    v4f bias = {};
    if (half == 0) bias = *(const v4f*)(b1 + h * 32 + k);
    float* dst = (half == 0) ? Abuf : Bbuf;
#pragma unroll
    for (int i = 0; i < 4; i++) {
      int rg = row0 + r0 + i; int b = rg >> 9; int ir = rg & 511;
      v4f o = (acc[i] + bias) * C2L2E;
      *(v4f*)(dst + ((b * 4 + h) * 512 + ir) * 32 + k) = o;
    }
  } else {
    int rg0 = row0 + r0; int b = rg0 >> 9; int ir0 = rg0 & 511;
#pragma unroll
    for (int u = 0; u < 4; u++) {
      int c = ct * 64 + c0 + u;
      v4f o = { acc[0][u], acc[1][u], acc[2][u], acc[3][u] };
      *(v4f*)(xpT + (b * 128 + c) * 512 + ir0) = o;
    }
  }
}

// ---------------------------------------------------------------------------
// dist2: D2[b][i][j] = max(sq_i + sq_j - 2 x_i.x_j, 0)   32x32 tiles, 2x2 micro
// ---------------------------------------------------------------------------
__global__ __launch_bounds__(256) void dist2_kernel(
    const float* __restrict__ x, const float* __restrict__ sq,
    float* __restrict__ D2)
{
  const int jt = blockIdx.x, it = blockIdx.y, b = blockIdx.z;
  const int t = threadIdx.x, tx = t & 15, ty = t >> 4;
  const int r0 = 2 * ty, c0 = 2 * tx;
  __shared__ v4f Xis[32 * 9], Xjs[32 * 9];
  const float* xb = x + b * 512 * 128;
  v4f acc[4] = {};
  const int row = t >> 3, k4l = t & 7, slot = (k4l + (row >> 1)) & 7;

  for (int dd0 = 0; dd0 < 128; dd0 += 32) {
    __syncthreads();
    Xis[row * 9 + slot] = *(const v4f*)(xb + (it * 32 + row) * 128 + dd0 + k4l * 4);
    Xjs[row * 9 + slot] = *(const v4f*)(xb + (jt * 32 + row) * 128 + dd0 + k4l * 4);
    __syncthreads();
#pragma unroll
    for (int k4 = 0; k4 < 8; k4++) {
      int sa = (k4 + ty) & 7, sb = (k4 + tx) & 7;
      v4f a0 = Xis[(r0 + 0) * 9 + sa], a1 = Xis[(r0 + 1) * 9 + sa];
      v4f b0 = Xjs[(c0 + 0) * 9 + sb], b1v = Xjs[(c0 + 1) * 9 + sb];
      acc[0] += a0 * b0; acc[1] += a0 * b1v;
      acc[2] += a1 * b0; acc[3] += a1 * b1v;
    }
  }
  float si0 = sq[b * 512 + it * 32 + r0], si1 = sq[b * 512 + it * 32 + r0 + 1];
  float sj0 = sq[b * 512 + jt * 32 + c0], sj1 = sq[b * 512 + jt * 32 + c0 + 1];
  v2f d0 = { fmaxf(si0 + sj0 - 2.f * hsum(acc[0]), 0.f),
             fmaxf(si0 + sj1 - 2.f * hsum(acc[1]), 0.f) };
  v2f d1 = { fmaxf(si1 + sj0 - 2.f * hsum(acc[2]), 0.f),
             fmaxf(si1 + sj1 - 2.f * hsum(acc[3]), 0.f) };
  float* dst = D2 + ((size_t)(b * 512 + it * 32 + r0)) * 512 + jt * 32 + c0;
  *(v2f*)dst = d0;
  *(v2f*)(dst + 512) = d1;
}

// ---------------------------------------------------------------------------
// adj: the hot kernel. ADJ[b][i][j] = mean_h exp(-d2 / (2*softplus(s)^2+eps))
//      s = b2[h] + sum_k tanh(A+B)*W2  with tanh = 1-2*rcp(1+exp2(A+B))
//      (A,B pre-scaled by 2log2e; sum_k W2 hoisted into the accumulator init)
// ---------------------------------------------------------------------------
__global__ __launch_bounds__(256) void adj_kernel(
    const float* __restrict__ Abuf, const float* __restrict__ Bbuf,
    const float* __restrict__ W2, const float* __restrict__ b2g,
    const float* __restrict__ D2, float* __restrict__ ADJ)
{
  const int jt = blockIdx.x, it = blockIdx.y, b = blockIdx.z;
  const int t = threadIdx.x, tx = t & 15, ty = t >> 4;
  const int r0 = 2 * ty, c0 = 2 * tx;
  __shared__ v4f As[32 * 9], Bs[32 * 9];
  __shared__ v4f W2s[32];
  __shared__ float hb[4];

  if (t < 32) W2s[t] = ((const v4f*)W2)[t];
  if (t < 4) {
    float s = b2g[t];
    for (int k = 0; k < 32; k++) s += W2[t * 32 + k];
    hb[t] = s;
  }

  const float* d2p = D2 + ((size_t)(b * 512 + it * 32 + r0)) * 512 + jt * 32 + c0;
  v2f d2a = *(const v2f*)d2p;
  v2f d2b = *(const v2f*)(d2p + 512);
  float d2L[4] = { d2a.x * NLOG2E, d2a.y * NLOG2E, d2b.x * NLOG2E, d2b.y * NLOG2E };

  const int row = t >> 3, k4l = t & 7, slot = (k4l + (row >> 1)) & 7;
  float accA[4] = {0.f, 0.f, 0.f, 0.f};

  // prefetch head 0
  v4f pa = *(const v4f*)(Abuf + ((size_t)((b * 4 + 0) * 512 + it * 32 + row)) * 32 + k4l * 4);
  v4f pb = *(const v4f*)(Bbuf + ((size_t)((b * 4 + 0) * 512 + jt * 32 + row)) * 32 + k4l * 4);

  for (int h = 0; h < 4; h++) {
    __syncthreads();
    As[row * 9 + slot] = pa;
    Bs[row * 9 + slot] = pb;
    __syncthreads();
    if (h < 3) {
      pa = *(const v4f*)(Abuf + ((size_t)((b * 4 + h + 1) * 512 + it * 32 + row)) * 32 + k4l * 4);
      pb = *(const v4f*)(Bbuf + ((size_t)((b * 4 + h + 1) * 512 + jt * 32 + row)) * 32 + k4l * 4);
    }
    float hbv = hb[h];
    float sacc[4] = { hbv, hbv, hbv, hbv };
#pragma unroll
    for (int k4 = 0; k4 < 8; k4++) {
      int sa = (k4 + ty) & 7, sb = (k4 + tx) & 7;
      v4f a0 = As[(r0 + 0) * 9 + sa], a1 = As[(r0 + 1) * 9 + sa];
      v4f b0 = Bs[(c0 + 0) * 9 + sb], b1v = Bs[(c0 + 1) * 9 + sb];
      v4f w2v = W2s[h * 8 + k4];
#pragma unroll
      for (int u = 0; u < 4; u++) {
        float wm = -2.f * w2v[u];
        float a0u = a0[u], a1u = a1[u], b0u = b0[u], b1u = b1v[u];
        float e;
        e = fexp2(a0u + b0u); sacc[0] = fmaf(wm, frcp(e + 1.f), sacc[0]);
        e = fexp2(a0u + b1u); sacc[1] = fmaf(wm, frcp(e + 1.f), sacc[1]);
        e = fexp2(a1u + b0u); sacc[2] = fmaf(wm, frcp(e + 1.f), sacc[2]);
        e = fexp2(a1u + b1u); sacc[3] = fmaf(wm, frcp(e + 1.f), sacc[3]);
      }
    }
#pragma unroll
    for (int p = 0; p < 4; p++) {
      float u2 = fexp2(sacc[p] * LOG2E);            // e^s
      float sg = LN2 * flog2(1.f + u2);             // softplus(s)
      float den = fmaf(2.f * sg, sg, 1e-6f);        // 2*sg^2 + eps
      accA[p] += fexp2(d2L[p] * frcp(den));         // exp(-d2/den)
    }
  }
  float* dst = ADJ + ((size_t)(b * 512 + it * 32 + r0)) * 512 + jt * 32 + c0;
  v2f o0 = { accA[0] * 0.25f, accA[1] * 0.25f };
  v2f o1 = { accA[2] * 0.25f, accA[3] * 0.25f };
  *(v2f*)dst = o0;
  *(v2f*)(dst + 512) = o1;
}

// ---------------------------------------------------------------------------
// out_gemm: partial[ks] = ADJ[:, kslice] @ xp[kslice, :]   (K split by 4)
// ---------------------------------------------------------------------------
__global__ __launch_bounds__(256) void out_gemm(
    const float* __restrict__ ADJ, const float* __restrict__ xpT,
    float* __restrict__ part)
{
  const int ct = blockIdx.x;            // 0..3 : 32-col tile
  const int it = blockIdx.y;            // 0..15: 32-row tile
  const int z = blockIdx.z; const int b = z >> 2, ks = z & 3;
  const int t = threadIdx.x, tx = t & 15, ty = t >> 4;
  const int r0 = 2 * ty, c0 = 2 * tx;
  __shared__ v4f Ajs[32 * 9], Xps[32 * 9];
  v4f acc[4] = {};
  const int row = t >> 3, k4l = t & 7, slot = (k4l + (row >> 1)) & 7;

  for (int k0 = ks * 128; k0 < ks * 128 + 128; k0 += 32) {
    __syncthreads();
    Ajs[row * 9 + slot] = *(const v4f*)(ADJ + ((size_t)(b * 512 + it * 32 + row)) * 512 + k0 + k4l * 4);
    Xps[row * 9 + slot] = *(const v4f*)(xpT + ((size_t)(b * 128 + ct * 32 + row)) * 512 + k0 + k4l * 4);
    __syncthreads();
#pragma unroll
    for (int k4 = 0; k4 < 8; k4++) {
      int sa = (k4 + ty) & 7, sb = (k4 + tx) & 7;
      v4f a0 = Ajs[(r0 + 0) * 9 + sa], a1 = Ajs[(r0 + 1) * 9 + sa];
      v4f b0 = Xps[(c0 + 0) * 9 + sb], b1v = Xps[(c0 + 1) * 9 + sb];
      acc[0] += a0 * b0; acc[1] += a0 * b1v;
      acc[2] += a1 * b0; acc[3] += a1 * b1v;
    }
  }
  float* dst = part + ((size_t)((ks * 4 + b) * 512 + it * 32 + r0)) * 128 + ct * 32 + c0;
  v2f o0 = { hsum(acc[0]), hsum(acc[1]) };
  v2f o1 = { hsum(acc[2]), hsum(acc[3]) };
  *(v2f*)dst = o0;
  *(v2f*)(dst + 128) = o1;
}

__global__ __launch_bounds__(256) void reduce_out(
    const float* __restrict__ part, const float* __restrict__ bp,
    float* __restrict__ out)
{
  int g = blockIdx.x * 256 + threadIdx.x;   // v4f index, 65536 total
  const v4f* p = (const v4f*)part;
  v4f s = p[g] + p[g + 65536] + p[g + 131072] + p[g + 196608];
  v4f bv = ((const v4f*)bp)[g & 31];
  ((v4f*)out)[g] = s + bv;
}

// ---------------------------------------------------------------------------
extern "C" void kernel_launch(void* const* d_in, const int* in_sizes, int n_in,
                              void* d_out, int out_size, void* d_ws, size_t ws_size,
                              hipStream_t stream) {
  const float* x  = (const float*)d_in[0];
  const float* W1 = (const float*)d_in[1];
  const float* b1 = (const float*)d_in[2];
  const float* W2 = (const float*)d_in[3];
  const float* b2 = (const float*)d_in[4];
  const float* Wp = (const float*)d_in[5];
  const float* bp = (const float*)d_in[6];
  float* out = (float*)d_out;

  float* ws  = (float*)d_ws;
  float* sq  = ws;                 // 2048
  float* A   = ws + 2048;          // 262144
  float* Bb  = A + 262144;         // 262144
  float* xpT = Bb + 262144;        // 262144
  float* D2  = xpT + 262144;       // 1048576
  float* ADJ = D2 + 1048576;       // 1048576
  float* part = D2;                // alias: D2 dead after adj_kernel

  prep_kernel<<<200, 256, 0, stream>>>(x, W1, b1, Wp, sq, A, Bb, xpT);
  dist2_kernel<<<dim3(16, 16, 4), 256, 0, stream>>>(x, sq, D2);
  adj_kernel<<<dim3(16, 16, 4), 256, 0, stream>>>(A, Bb, W2, b2, D2, ADJ);
  out_gemm<<<dim3(4, 16, 16), 256, 0, stream>>>(ADJ, xpT, part);
  reduce_out<<<256, 256, 0, stream>>>(part, bp, out);
}

// Round 2
// 67.437 us; speedup vs baseline: 1.0131x; 1.0131x over previous
//
#include <hip/hip_runtime.h>

typedef float v4f __attribute__((ext_vector_type(4)));
typedef float v2f __attribute__((ext_vector_type(2)));

#define LOG2E  1.4426950408889634f
#define NLOG2E (-1.4426950408889634f)
#define C2L2E  2.8853900817779268f   // 2*log2(e)
#define LN2    0.6931471805599453f

__device__ __forceinline__ float fexp2(float x){ return __builtin_amdgcn_exp2f(x); }
__device__ __forceinline__ float flog2(float x){ return __builtin_amdgcn_logf(x); }
__device__ __forceinline__ float frcp (float x){ return __builtin_amdgcn_rcpf(x); }
__device__ __forceinline__ float hsum(v4f v){ return (v.x+v.y)+(v.z+v.w); }

// ---------------------------------------------------------------------------
// prep: bid 0..127  : A/B = (x @ W1half (+b1)) * 2log2e   (X[2048x128] @ W[128x256])
//       bid 128..191: xpT = (x @ Wp)^T                    (X[2048x128] @ Wp[128x128])
//       bid 192..199: sq[row] = ||x_row||^2
// ---------------------------------------------------------------------------
__global__ __launch_bounds__(256) void prep_kernel(
    const float* __restrict__ x, const float* __restrict__ W1,
    const float* __restrict__ b1, const float* __restrict__ Wp,
    float* __restrict__ sq, float* __restrict__ Abuf,
    float* __restrict__ Bbuf, float* __restrict__ xpT)
{
  const int bid = blockIdx.x, t = threadIdx.x;
  if (bid >= 192) {                       // ---- sq ----
    int row = (bid - 192) * 256 + t;      // 0..2047
    const v4f* xv = (const v4f*)(x + row * 128);
    float s = 0.f;
#pragma unroll
    for (int q = 0; q < 32; q++) { v4f v = xv[q]; s += hsum(v * v); }
    sq[row] = s;
    return;
  }
  __shared__ v4f Xs[64 * 9];              // 64 rows x 8 f4, pad 9, slot-swizzled
  __shared__ v4f Ws[32 * 16];             // 32 dd  x 16 f4 (64 cols)
  const bool isAB = bid < 128;
  int it, ct;
  if (isAB) { it = bid >> 2; ct = bid & 3; }
  else      { int q = bid - 128; it = q >> 1; ct = q & 1; }
  const int row0 = it * 64;
  const int tx = t & 15, ty = t >> 4;
  const int r0 = ty * 4, c0 = tx * 4;
  v4f acc[4] = {};                        // acc[i] over 4 cols

  for (int dd0 = 0; dd0 < 128; dd0 += 32) {
    __syncthreads();
#pragma unroll
    for (int s2 = 0; s2 < 2; s2++) {      // stage X (coalesced), swizzled slot
      int idx = t + s2 * 256;
      int row = idx >> 3, k4 = idx & 7;
      v4f v = *(const v4f*)(x + (row0 + row) * 128 + dd0 + k4 * 4);
      Xs[row * 9 + ((k4 + (row >> 2)) & 7)] = v;
    }
#pragma unroll
    for (int s2 = 0; s2 < 2; s2++) {      // stage W (f4 along cols)
      int idx = t + s2 * 256;
      int dd = idx >> 4, cf4 = idx & 15;
      v4f v;
      if (isAB) {
        int cl = cf4 * 4; int half = cl >> 5; int k = cl & 31;
        v = *(const v4f*)(W1 + (ct * 256 + half * 128 + dd0 + dd) * 32 + k);
      } else {
        v = *(const v4f*)(Wp + (dd0 + dd) * 128 + ct * 64 + cf4 * 4);
      }
      Ws[dd * 16 + cf4] = v;
    }
    __syncthreads();
#pragma unroll
    for (int dd4 = 0; dd4 < 8; dd4++) {
      int sa = (dd4 + ty) & 7;
      v4f a0 = Xs[(r0 + 0) * 9 + sa], a1 = Xs[(r0 + 1) * 9 + sa];
      v4f a2 = Xs[(r0 + 2) * 9 + sa], a3 = Xs[(r0 + 3) * 9 + sa];
#pragma unroll
      for (int u = 0; u < 4; u++) {
        v4f bv = Ws[(dd4 * 4 + u) * 16 + tx];
        acc[0] += a0[u] * bv; acc[1] += a1[u] * bv;
        acc[2] += a2[u] * bv; acc[3] += a3[u] * bv;
      }
    }
  }

  if (isAB) {
    const int h = ct; const int half = c0 >> 5; const int k = c0 & 31;
    v4f bias = {};
    if (half == 0) bias = *(const v4f*)(b1 + h * 32 + k);
    float* dst = (half == 0) ? Abuf : Bbuf;
#pragma unroll
    for (int i = 0; i < 4; i++) {
      int rg = row0 + r0 + i; int b = rg >> 9; int ir = rg & 511;
      v4f o = (acc[i] + bias) * C2L2E;
      *(v4f*)(dst + ((b * 4 + h) * 512 + ir) * 32 + k) = o;
    }
  } else {
    int rg0 = row0 + r0; int b = rg0 >> 9; int ir0 = rg0 & 511;
#pragma unroll
    for (int u = 0; u < 4; u++) {
      int c = ct * 64 + c0 + u;
      v4f o = { acc[0][u], acc[1][u], acc[2][u], acc[3][u] };
      *(v4f*)(xpT + (b * 128 + c) * 512 + ir0) = o;
    }
  }
}

// ---------------------------------------------------------------------------
// adj (fused dist2 + dgf): per (b, 32x32 tile):
//   phase 1: gram over K=128 -> d2 = max(sq_i + sq_j - 2 x_i.x_j, 0)
//   phase 2: per head h: s = hb[h] - 2*sum_k rcp(1+exp2(A_i+B_j))*W2
//            sigma = softplus(s); acc += exp(-d2/(2 sigma^2+eps))
//   ADJ = acc/4.  A,B pre-scaled by 2log2e; sum_k W2 + b2 hoisted into hb.
// ---------------------------------------------------------------------------
__global__ __launch_bounds__(256) void adj_kernel(
    const float* __restrict__ x, const float* __restrict__ sq,
    const float* __restrict__ Abuf, const float* __restrict__ Bbuf,
    const float* __restrict__ W2, const float* __restrict__ b2g,
    float* __restrict__ ADJ)
{
  const int jt = blockIdx.x, it = blockIdx.y, b = blockIdx.z;
  const int t = threadIdx.x, tx = t & 15, ty = t >> 4;
  const int r0 = 2 * ty, c0 = 2 * tx;
  __shared__ v4f As[32 * 9], Bs[32 * 9];
  __shared__ v4f W2s[32];
  __shared__ float hb[4];

  if (t < 32) W2s[t] = ((const v4f*)W2)[t];
  if (t < 4) {
    float s = b2g[t];
    for (int k = 0; k < 32; k++) s += W2[t * 32 + k];
    hb[t] = s;
  }

  const int row = t >> 3, k4l = t & 7, slot = (k4l + (row >> 1)) & 7;
  const float* xb = x + b * 512 * 128;

  // prefetch head 0 A/B (hidden under the gram phase)
  v4f pa = *(const v4f*)(Abuf + ((size_t)((b * 4 + 0) * 512 + it * 32 + row)) * 32 + k4l * 4);
  v4f pb = *(const v4f*)(Bbuf + ((size_t)((b * 4 + 0) * 512 + jt * 32 + row)) * 32 + k4l * 4);

  // ---- phase 1: gram / dist2 (reuses As/Bs) ----
  v4f gacc[4] = {};
  for (int dd0 = 0; dd0 < 128; dd0 += 32) {
    __syncthreads();
    As[row * 9 + slot] = *(const v4f*)(xb + (it * 32 + row) * 128 + dd0 + k4l * 4);
    Bs[row * 9 + slot] = *(const v4f*)(xb + (jt * 32 + row) * 128 + dd0 + k4l * 4);
    __syncthreads();
#pragma unroll
    for (int k4 = 0; k4 < 8; k4++) {
      int sa = (k4 + ty) & 7, sb = (k4 + tx) & 7;
      v4f a0 = As[(r0 + 0) * 9 + sa], a1 = As[(r0 + 1) * 9 + sa];
      v4f b0 = Bs[(c0 + 0) * 9 + sb], b1v = Bs[(c0 + 1) * 9 + sb];
      gacc[0] += a0 * b0; gacc[1] += a0 * b1v;
      gacc[2] += a1 * b0; gacc[3] += a1 * b1v;
    }
  }
  float si0 = sq[b * 512 + it * 32 + r0], si1 = sq[b * 512 + it * 32 + r0 + 1];
  float sj0 = sq[b * 512 + jt * 32 + c0], sj1 = sq[b * 512 + jt * 32 + c0 + 1];
  float d2L[4] = {
    fmaxf(si0 + sj0 - 2.f * hsum(gacc[0]), 0.f) * NLOG2E,
    fmaxf(si0 + sj1 - 2.f * hsum(gacc[1]), 0.f) * NLOG2E,
    fmaxf(si1 + sj0 - 2.f * hsum(gacc[2]), 0.f) * NLOG2E,
    fmaxf(si1 + sj1 - 2.f * hsum(gacc[3]), 0.f) * NLOG2E };

  // ---- phase 2: heads ----
  float accA[4] = {0.f, 0.f, 0.f, 0.f};
  for (int h = 0; h < 4; h++) {
    __syncthreads();
    As[row * 9 + slot] = pa;
    Bs[row * 9 + slot] = pb;
    __syncthreads();
    if (h < 3) {
      pa = *(const v4f*)(Abuf + ((size_t)((b * 4 + h + 1) * 512 + it * 32 + row)) * 32 + k4l * 4);
      pb = *(const v4f*)(Bbuf + ((size_t)((b * 4 + h + 1) * 512 + jt * 32 + row)) * 32 + k4l * 4);
    }
    float hbv = hb[h];
    float sacc[4] = { hbv, hbv, hbv, hbv };
#pragma unroll
    for (int k4 = 0; k4 < 8; k4++) {
      int sa = (k4 + ty) & 7, sb = (k4 + tx) & 7;
      v4f a0 = As[(r0 + 0) * 9 + sa], a1 = As[(r0 + 1) * 9 + sa];
      v4f b0 = Bs[(c0 + 0) * 9 + sb], b1v = Bs[(c0 + 1) * 9 + sb];
      v4f w2v = W2s[h * 8 + k4];
#pragma unroll
      for (int u = 0; u < 4; u++) {
        float wm = -2.f * w2v[u];
        float a0u = a0[u], a1u = a1[u], b0u = b0[u], b1u = b1v[u];
        float e;
        e = fexp2(a0u + b0u); sacc[0] = fmaf(wm, frcp(e + 1.f), sacc[0]);
        e = fexp2(a0u + b1u); sacc[1] = fmaf(wm, frcp(e + 1.f), sacc[1]);
        e = fexp2(a1u + b0u); sacc[2] = fmaf(wm, frcp(e + 1.f), sacc[2]);
        e = fexp2(a1u + b1u); sacc[3] = fmaf(wm, frcp(e + 1.f), sacc[3]);
      }
    }
#pragma unroll
    for (int p = 0; p < 4; p++) {
      float u2 = fexp2(sacc[p] * LOG2E);            // e^s
      float sg = LN2 * flog2(1.f + u2);             // softplus(s)
      float den = fmaf(2.f * sg, sg, 1e-6f);        // 2*sg^2 + eps
      accA[p] += fexp2(d2L[p] * frcp(den));         // exp(-d2/den)
    }
  }
  float* dst = ADJ + ((size_t)(b * 512 + it * 32 + r0)) * 512 + jt * 32 + c0;
  v2f o0 = { accA[0] * 0.25f, accA[1] * 0.25f };
  v2f o1 = { accA[2] * 0.25f, accA[3] * 0.25f };
  *(v2f*)dst = o0;
  *(v2f*)(dst + 512) = o1;
}

// ---------------------------------------------------------------------------
// out: out[b,i,c] = sum_j ADJ[b,i,j] * xpT[b,c,j] + bp[c]   (full K=512)
// ---------------------------------------------------------------------------
__global__ __launch_bounds__(256) void out_kernel(
    const float* __restrict__ ADJ, const float* __restrict__ xpT,
    const float* __restrict__ bp, float* __restrict__ out)
{
  const int ct = blockIdx.x;            // 0..3 : 32-col tile
  const int it = blockIdx.y;            // 0..15: 32-row tile
  const int b = blockIdx.z;             // 0..3
  const int t = threadIdx.x, tx = t & 15, ty = t >> 4;
  const int r0 = 2 * ty, c0 = 2 * tx;
  __shared__ v4f Ajs[32 * 9], Xps[32 * 9];
  v4f acc[4] = {};
  const int row = t >> 3, k4l = t & 7, slot = (k4l + (row >> 1)) & 7;

  for (int k0 = 0; k0 < 512; k0 += 32) {
    __syncthreads();
    Ajs[row * 9 + slot] = *(const v4f*)(ADJ + ((size_t)(b * 512 + it * 32 + row)) * 512 + k0 + k4l * 4);
    Xps[row * 9 + slot] = *(const v4f*)(xpT + ((size_t)(b * 128 + ct * 32 + row)) * 512 + k0 + k4l * 4);
    __syncthreads();
#pragma unroll
    for (int k4 = 0; k4 < 8; k4++) {
      int sa = (k4 + ty) & 7, sb = (k4 + tx) & 7;
      v4f a0 = Ajs[(r0 + 0) * 9 + sa], a1 = Ajs[(r0 + 1) * 9 + sa];
      v4f b0 = Xps[(c0 + 0) * 9 + sb], b1v = Xps[(c0 + 1) * 9 + sb];
      acc[0] += a0 * b0; acc[1] += a0 * b1v;
      acc[2] += a1 * b0; acc[3] += a1 * b1v;
    }
  }
  float bp0 = bp[ct * 32 + c0], bp1 = bp[ct * 32 + c0 + 1];
  float* dst = out + ((size_t)(b * 512 + it * 32 + r0)) * 128 + ct * 32 + c0;
  v2f o0 = { hsum(acc[0]) + bp0, hsum(acc[1]) + bp1 };
  v2f o1 = { hsum(acc[2]) + bp0, hsum(acc[3]) + bp1 };
  *(v2f*)dst = o0;
  *(v2f*)(dst + 128) = o1;
}

// ---------------------------------------------------------------------------
extern "C" void kernel_launch(void* const* d_in, const int* in_sizes, int n_in,
                              void* d_out, int out_size, void* d_ws, size_t ws_size,
                              hipStream_t stream) {
  const float* x  = (const float*)d_in[0];
  const float* W1 = (const float*)d_in[1];
  const float* b1 = (const float*)d_in[2];
  const float* W2 = (const float*)d_in[3];
  const float* b2 = (const float*)d_in[4];
  const float* Wp = (const float*)d_in[5];
  const float* bp = (const float*)d_in[6];
  float* out = (float*)d_out;

  float* ws  = (float*)d_ws;
  float* sq  = ws;                 // 2048
  float* A   = ws + 2048;          // 262144
  float* Bb  = A + 262144;         // 262144
  float* xpT = Bb + 262144;        // 262144
  float* ADJ = xpT + 262144;       // 1048576

  prep_kernel<<<200, 256, 0, stream>>>(x, W1, b1, Wp, sq, A, Bb, xpT);
  adj_kernel<<<dim3(16, 16, 4), 256, 0, stream>>>(x, sq, A, Bb, W2, b2, ADJ);
  out_kernel<<<dim3(4, 16, 4), 256, 0, stream>>>(ADJ, xpT, bp, out);
}